// Round 12
// baseline (649.631 us; speedup 1.0000x reference)
//
#include <hip/hip_runtime.h>
#include <math.h>

#define LSEQ 2304
#define DM 128
#define DI 256
#define DS 16
#define RK 8
#define NCH 576     // 4-row chunks
#define CLEN 4
#define NG 24       // carry groups
#define GS 24       // chunks per group (NG*GS == NCH)
#define NSI (DI*DS) // 4096 state indices
#define EPSF 1e-5f

__device__ __forceinline__ float silu_f(float s) { return s / (1.f + __expf(-s)); }
__device__ __forceinline__ float softplus_f(float x) { return (x > 20.f) ? x : log1pf(__expf(x)); }

// ---------------------------------------------------------------------------
// IN: in-proj GEMM + conv4 + silu -> xc ; silu(z) -> sz.
// grid (288, 4): 8-row x 128-col tiles. y=0/1: x-halves (conv, 3-row halo
// recomputed in-register); y=2/3: z-halves. block 256 = 128 cols x 2 rowgroups.
template<bool FIRST>
__global__ __launch_bounds__(256, 4)
void k_in(const float* __restrict__ seq, const float* __restrict__ x0,
          const float* __restrict__ Wi,
          const float* __restrict__ cw, const float* __restrict__ cbias,
          float* __restrict__ xc_g, float* __restrict__ sz_g) {
    __shared__ float As[11 * 128];   // seq rows l0-3 .. l0+7
    const int l0 = blockIdx.x * 8;
    const int half = blockIdx.y & 1;
    const bool isZ = blockIdx.y >= 2;
    const int tid = threadIdx.x;

    for (int idx = tid; idx < 11 * 128; idx += 256) {
        const int r = idx >> 7, cc = idx & 127;
        const int l = l0 - 3 + r;
        As[idx] = (l >= 0) ? (FIRST ? x0[cc * LSEQ + l] : seq[l * DM + cc]) : 0.f;
    }
    __syncthreads();

    const int c = tid & 127;
    const int rg = tid >> 7;          // 0..1 -> out rows rg*4 .. rg*4+3
    const int d = half * 128 + c;

    if (!isZ) {
        float ax[7] = {0.f, 0.f, 0.f, 0.f, 0.f, 0.f, 0.f};
        for (int k4 = 0; k4 < 32; ++k4) {
            float bv[4];
#pragma unroll
            for (int u = 0; u < 4; ++u) bv[u] = Wi[(k4 * 4 + u) * 512 + d];
#pragma unroll
            for (int r = 0; r < 7; ++r) {
                const float4 a4 = *(const float4*)&As[(rg * 4 + r) * 128 + k4 * 4];
                ax[r] += a4.x * bv[0] + a4.y * bv[1] + a4.z * bv[2] + a4.w * bv[3];
            }
        }
        const float w0 = cw[d * 4 + 0], w1 = cw[d * 4 + 1];
        const float w2 = cw[d * 4 + 2], w3 = cw[d * 4 + 3];
        const float cbv = cbias[d];
#pragma unroll
        for (int rr = 0; rr < 4; ++rr) {
            const float v = silu_f(cbv + w0 * ax[rr] + w1 * ax[rr + 1] +
                                   w2 * ax[rr + 2] + w3 * ax[rr + 3]);
            xc_g[(l0 + rg * 4 + rr) * DI + d] = v;
        }
    } else {
        float az[4] = {0.f, 0.f, 0.f, 0.f};
        for (int k4 = 0; k4 < 32; ++k4) {
            float bv[4];
#pragma unroll
            for (int u = 0; u < 4; ++u) bv[u] = Wi[(k4 * 4 + u) * 512 + 256 + d];
#pragma unroll
            for (int r = 0; r < 4; ++r) {
                const float4 a4 = *(const float4*)&As[(rg * 4 + r + 3) * 128 + k4 * 4];
                az[r] += a4.x * bv[0] + a4.y * bv[1] + a4.z * bv[2] + a4.w * bv[3];
            }
        }
#pragma unroll
        for (int rr = 0; rr < 4; ++rr)
            sz_g[(l0 + rg * 4 + rr) * DI + d] = silu_f(az[rr]);
    }
}

// ---------------------------------------------------------------------------
// MID: xc @ Wx -> (dtr, B, C) ; dt = softplus(dtr@Wdt+bdt) ; chunk scan -> P,S.
// grid 576 (4-row chunks); block 256. xproj K-split x4 across all threads.
__global__ __launch_bounds__(256, 4)
void k_mid2(const float* __restrict__ xc_g,
            const float* __restrict__ Wx,
            const float* __restrict__ Wdt, const float* __restrict__ bdt,
            const float* __restrict__ Alog,
            float* __restrict__ dbl_g, float* __restrict__ dt_g,
            float* __restrict__ P, float* __restrict__ S) {
    __shared__ float xcs[CLEN * 256];
    __shared__ float part[4 * 160];
    __shared__ float dtrs[CLEN * 8];
    __shared__ float dbls[CLEN * 32];
    const int c = blockIdx.x;
    const int l0 = c * CLEN;
    const int tid = threadIdx.x;
    const int d = tid;

    // stage 4 xc rows: 256 float4, fully coalesced
    ((float4*)xcs)[tid] = ((const float4*)&xc_g[l0 * DI])[tid];
    __syncthreads();

    // xproj: 160 outputs x 4 K-quarters = 640 tasks over 256 threads
    for (int task = tid; task < 640; task += 256) {
        const int kc = task / 160;
        const int o = task - kc * 160;
        const int r = o / 40, j = o - r * 40;
        const float* xr = &xcs[r * 256 + kc * 64];
        const float* wp = &Wx[(kc * 64) * 40 + j];
        float acc = 0.f;
#pragma unroll 8
        for (int k = 0; k < 64; ++k) acc += xr[k] * wp[k * 40];
        part[kc * 160 + o] = acc;
    }
    __syncthreads();
    if (tid < 160) {
        const float acc = part[tid] + part[160 + tid] + part[320 + tid] + part[480 + tid];
        const int r = tid / 40, j = tid - r * 40;
        if (j < RK) dtrs[r * 8 + j] = acc;
        else {
            dbls[r * 32 + (j - 8)] = acc;
            dbl_g[(l0 + r) * 32 + (j - 8)] = acc;
        }
    }
    __syncthreads();

    // dt = softplus(dtr @ Wdt + bdt)
    float dtv[CLEN], xcv[CLEN];
    {
        float wdt[8];
#pragma unroll
        for (int q = 0; q < 8; ++q) wdt[q] = Wdt[q * DI + d];
        const float bdv = bdt[d];
#pragma unroll
        for (int r = 0; r < CLEN; ++r) {
            float acc = bdv;
#pragma unroll
            for (int q = 0; q < 8; ++q) acc += dtrs[r * 8 + q] * wdt[q];
            dtv[r] = softplus_f(acc);
            dt_g[(l0 + r) * DI + d] = dtv[r];
            xcv[r] = xcs[r * 256 + d];
        }
    }

    // chunk-local scan (thread d holds 16 states)
    float A[16], pr[16], hs[16];
#pragma unroll
    for (int v = 0; v < 4; ++v) {
        const float4 a4 = *(const float4*)&Alog[d * DS + v * 4];
        A[v * 4 + 0] = -__expf(a4.x);
        A[v * 4 + 1] = -__expf(a4.y);
        A[v * 4 + 2] = -__expf(a4.z);
        A[v * 4 + 3] = -__expf(a4.w);
    }
#pragma unroll
    for (int s = 0; s < 16; ++s) { pr[s] = 1.f; hs[s] = 0.f; }
#pragma unroll
    for (int t = 0; t < CLEN; ++t) {
        const float dtt = dtv[t];
        const float uv = dtt * xcv[t];
        const float* Brow = &dbls[t * 32];
#pragma unroll
        for (int s = 0; s < 16; ++s) {
            const float e = __expf(dtt * A[s]);
            pr[s] *= e;
            hs[s] = e * hs[s] + uv * Brow[s];
        }
    }
    const int base = c * NSI + d * DS;
#pragma unroll
    for (int v = 0; v < 4; ++v) {
        *(float4*)&P[base + v * 4] =
            make_float4(pr[v * 4], pr[v * 4 + 1], pr[v * 4 + 2], pr[v * 4 + 3]);
        *(float4*)&S[base + v * 4] =
            make_float4(hs[v * 4], hs[v * 4 + 1], hs[v * 4 + 2], hs[v * 4 + 3]);
    }
}

// ---------------------------------------------------------------------------
// CARRY1: per group of GS chunks, in place: P -> prefix product, S -> local
// carry; emit group aggregates (NOT converted to carries — tail does that
// redundantly). grid (NG, 16); block 256.
__global__ __launch_bounds__(256, 4)
void k_carry1(float* __restrict__ P, float* __restrict__ S,
              float* __restrict__ Pg, float* __restrict__ Sg) {
    const int g = blockIdx.x;
    const int i = blockIdx.y * 256 + threadIdx.x;
    float G = 0.f, Pp = 1.f;
    const int base = g * GS * NSI + i;
#pragma unroll 8
    for (int k = 0; k < GS; ++k) {
        const int idx = base + k * NSI;
        const float p = P[idx];
        const float s = S[idx];
        S[idx] = G;
        P[idx] = Pp;
        G = p * G + s;
        Pp *= p;
    }
    Pg[g * NSI + i] = Pp;
    Sg[g * NSI + i] = G;
}

// ---------------------------------------------------------------------------
// TAIL: group carry recomputed in-register from (Pg,Sg) aggregates (<=23
// L2-hot float4 combine steps); h0 = Sloc + Pprefix * Gcarry; re-scan + gate
// + out-GEMM (K-split x4) + rmsnorm. grid 576; block 256.
template<bool LAST>
__global__ __launch_bounds__(256, 3)
void k_tail(const float* __restrict__ dt_g, const float* __restrict__ xc_g,
            const float* __restrict__ dbl_g, const float* __restrict__ Alog,
            const float* __restrict__ Sloc, const float* __restrict__ Ppre,
            const float* __restrict__ Pg, const float* __restrict__ Sg,
            const float* __restrict__ Dp,
            const float* __restrict__ sz_g, const float* __restrict__ Wo,
            const float* __restrict__ rmsw, float* __restrict__ seq,
            float* __restrict__ out) {
    __shared__ float dbls[CLEN * 32];     // 128
    __shared__ float Ys[CLEN * 256];
    __shared__ float partO[4 * CLEN * 128];   // [kg][r][cc]
    __shared__ float Os[CLEN * 129];
    __shared__ float red[CLEN * 32];
    __shared__ float scaleS[CLEN];
    const int c = blockIdx.x;
    const int g = c / GS;
    const int l0 = c * CLEN;
    const int tid = threadIdx.x;
    const int d = tid;

    if (tid < CLEN * 32) dbls[tid] = dbl_g[l0 * 32 + tid];

    // group carry: G = scan over groups 0..g-1 of (Pg, Sg)
    float G[16];
#pragma unroll
    for (int s = 0; s < 16; ++s) G[s] = 0.f;
    for (int gg = 0; gg < g; ++gg) {
        const int gb = gg * NSI + d * DS;
#pragma unroll
        for (int v = 0; v < 4; ++v) {
            const float4 p4 = *(const float4*)&Pg[gb + v * 4];
            const float4 s4 = *(const float4*)&Sg[gb + v * 4];
            G[v * 4 + 0] = p4.x * G[v * 4 + 0] + s4.x;
            G[v * 4 + 1] = p4.y * G[v * 4 + 1] + s4.y;
            G[v * 4 + 2] = p4.z * G[v * 4 + 2] + s4.z;
            G[v * 4 + 3] = p4.w * G[v * 4 + 3] + s4.w;
        }
    }

    float A[16], h[16];
#pragma unroll
    for (int v = 0; v < 4; ++v) {
        const float4 a4 = *(const float4*)&Alog[d * DS + v * 4];
        A[v * 4 + 0] = -__expf(a4.x);
        A[v * 4 + 1] = -__expf(a4.y);
        A[v * 4 + 2] = -__expf(a4.z);
        A[v * 4 + 3] = -__expf(a4.w);
        const float4 s4 = *(const float4*)&Sloc[c * NSI + d * DS + v * 4];
        const float4 p4 = *(const float4*)&Ppre[c * NSI + d * DS + v * 4];
        h[v * 4 + 0] = s4.x + p4.x * G[v * 4 + 0];
        h[v * 4 + 1] = s4.y + p4.y * G[v * 4 + 1];
        h[v * 4 + 2] = s4.z + p4.z * G[v * 4 + 2];
        h[v * 4 + 3] = s4.w + p4.w * G[v * 4 + 3];
    }
    float dtv[CLEN], xcv[CLEN], szv[CLEN];
#pragma unroll
    for (int r = 0; r < CLEN; ++r) {
        dtv[r] = dt_g[(l0 + r) * DI + d];
        xcv[r] = xc_g[(l0 + r) * DI + d];
        szv[r] = sz_g[(l0 + r) * DI + d];
    }
    const float dskip = Dp[d];
    __syncthreads();
#pragma unroll
    for (int t = 0; t < CLEN; ++t) {
        const float dtt = dtv[t];
        const float uv = dtt * xcv[t];
        float sum = 0.f;
#pragma unroll
        for (int s = 0; s < 16; ++s) {
            const float e = __expf(dtt * A[s]);
            h[s] = e * h[s] + uv * dbls[t * 32 + s];
            sum += h[s] * dbls[t * 32 + 16 + s];
        }
        Ys[t * 256 + d] = (sum + dskip * xcv[t]) * szv[t];
    }
    __syncthreads();

    // out-GEMM: 64 cc-pairs x 4 K-groups (K=64 each), float2 Wo loads
    {
        const int ccp = tid & 63;
        const int kg = tid >> 6;
        float acc[CLEN][2];
#pragma unroll
        for (int r = 0; r < CLEN; ++r) { acc[r][0] = 0.f; acc[r][1] = 0.f; }
        const float* wp = &Wo[(kg * 64) * DM + ccp * 2];
        const float* yp = &Ys[kg * 64];
#pragma unroll 8
        for (int k = 0; k < 64; ++k) {
            const float2 w2 = *(const float2*)(wp + k * DM);
#pragma unroll
            for (int r = 0; r < CLEN; ++r) {
                const float yv = yp[r * 256 + k];
                acc[r][0] += yv * w2.x;
                acc[r][1] += yv * w2.y;
            }
        }
#pragma unroll
        for (int r = 0; r < CLEN; ++r) {
            partO[(kg * CLEN + r) * 128 + ccp * 2 + 0] = acc[r][0];
            partO[(kg * CLEN + r) * 128 + ccp * 2 + 1] = acc[r][1];
        }
        __syncthreads();
        for (int idx = tid; idx < CLEN * 128; idx += 256) {
            const int r = idx >> 7, cc = idx & 127;
            Os[r * 129 + cc] = partO[(0 * CLEN + r) * 128 + cc] +
                               partO[(1 * CLEN + r) * 128 + cc] +
                               partO[(2 * CLEN + r) * 128 + cc] +
                               partO[(3 * CLEN + r) * 128 + cc];
        }
        __syncthreads();
    }

    // rmsnorm + store
    if (tid < CLEN * 32) {
        const int r = tid >> 5, part = tid & 31;
        float ss = 0.f;
#pragma unroll
        for (int i = 0; i < 4; ++i) {
            const float v = Os[r * 129 + part * 4 + i];
            ss += v * v;
        }
        red[tid] = ss;
    }
    __syncthreads();
    if (tid < CLEN) {
        float ss = 0.f;
#pragma unroll
        for (int p = 0; p < 32; ++p) ss += red[tid * 32 + p];
        scaleS[tid] = rsqrtf(ss * (1.f / DM) + EPSF);
    }
    __syncthreads();
    if (LAST) {
        for (int idx = tid; idx < CLEN * DM; idx += 256) {
            const int r = idx >> 7, cc = idx & 127;
            out[cc * LSEQ + (l0 + r)] = Os[r * 129 + cc] * scaleS[r] * rmsw[cc];
        }
    } else {
        for (int idx = tid; idx < CLEN * DM; idx += 256) {
            const int r = idx >> 7, cc = idx & 127;
            seq[(l0 + r) * DM + cc] = Os[r * 129 + cc] * scaleS[r] * rmsw[cc];
        }
    }
}

// ---------------------------------------------------------------------------
extern "C" void kernel_launch(void* const* d_in, const int* in_sizes, int n_in,
                              void* d_out, int out_size, void* d_ws, size_t ws_size,
                              hipStream_t stream) {
    const float* x    = (const float*)d_in[0];
    const float* W_in = (const float*)d_in[1];
    const float* cw   = (const float*)d_in[2];
    const float* cb   = (const float*)d_in[3];
    const float* Wx   = (const float*)d_in[4];
    const float* Wdt  = (const float*)d_in[5];
    const float* bdt  = (const float*)d_in[6];
    const float* Alog = (const float*)d_in[7];
    const float* Dp   = (const float*)d_in[8];
    const float* Wo   = (const float*)d_in[9];
    const float* rmsw = (const float*)d_in[10];
    float* out = (float*)d_out;

    float* ws   = (float*)d_ws;
    float* seq  = ws; ws += LSEQ * DM;
    float* szb  = ws; ws += LSEQ * DI;
    float* xcb  = ws; ws += LSEQ * DI;
    float* dtb  = ws; ws += LSEQ * DI;
    float* dblb = ws; ws += LSEQ * 32;
    float* Pb   = ws; ws += NCH * NSI;
    float* Sb   = ws; ws += NCH * NSI;
    float* Pgb  = ws; ws += NG * NSI;
    float* Sgb  = ws; ws += NG * NSI;

    for (int layer = 0; layer < 8; ++layer) {
        const float* Wi_l   = W_in + (size_t)layer * DM * 512;
        const float* cw_l   = cw   + (size_t)layer * DI * 4;
        const float* cb_l   = cb   + (size_t)layer * DI;
        const float* Wx_l   = Wx   + (size_t)layer * DI * 40;
        const float* Wdt_l  = Wdt  + (size_t)layer * RK * DI;
        const float* bdt_l  = bdt  + (size_t)layer * DI;
        const float* Alog_l = Alog + (size_t)layer * DI * DS;
        const float* Dp_l   = Dp   + (size_t)layer * DI;
        const float* Wo_l   = Wo   + (size_t)layer * DI * DM;
        const float* rmsw_l = rmsw + (size_t)layer * DM;

        if (layer == 0)
            k_in<true><<<dim3(288, 4), 256, 0, stream>>>(seq, x, Wi_l, cw_l, cb_l,
                                                         xcb, szb);
        else
            k_in<false><<<dim3(288, 4), 256, 0, stream>>>(seq, x, Wi_l, cw_l, cb_l,
                                                          xcb, szb);

        k_mid2<<<NCH, 256, 0, stream>>>(xcb, Wx_l, Wdt_l, bdt_l, Alog_l,
                                        dblb, dtb, Pb, Sb);

        k_carry1<<<dim3(NG, 16), 256, 0, stream>>>(Pb, Sb, Pgb, Sgb);

        if (layer == 7)
            k_tail<true><<<NCH, 256, 0, stream>>>(dtb, xcb, dblb, Alog_l, Sb, Pb,
                                                  Pgb, Sgb, Dp_l, szb, Wo_l,
                                                  rmsw_l, seq, out);
        else
            k_tail<false><<<NCH, 256, 0, stream>>>(dtb, xcb, dblb, Alog_l, Sb, Pb,
                                                   Pgb, Sgb, Dp_l, szb, Wo_l,
                                                   rmsw_l, seq, out);
    }
}

// Round 13
// 558.984 us; speedup vs baseline: 1.1622x; 1.1622x over previous
//
#include <hip/hip_runtime.h>
#include <math.h>

#define LSEQ 2304
#define DM 128
#define DI 256
#define DS 16
#define RK 8
#define NCH 576     // 4-row chunks
#define CLEN 4
#define NG 24       // carry groups
#define GS 24       // chunks per group (NG*GS == NCH)
#define NSI (DI*DS) // 4096 state indices
#define EPSF 1e-5f

__device__ __forceinline__ float silu_f(float s) { return s / (1.f + __expf(-s)); }
__device__ __forceinline__ float softplus_f(float x) { return (x > 20.f) ? x : log1pf(__expf(x)); }

// ---------------------------------------------------------------------------
// IN: in-proj GEMM + conv4 + silu -> xc ; silu(z) -> sz.
// grid (288, 4): 8-row x 128-col tiles. y=0/1: x-halves (conv, 3-row halo
// recomputed in-register); y=2/3: z-halves. block 256 = 128 cols x 2 rowgroups.
template<bool FIRST>
__global__ __launch_bounds__(256, 4)
void k_in(const float* __restrict__ seq, const float* __restrict__ x0,
          const float* __restrict__ Wi,
          const float* __restrict__ cw, const float* __restrict__ cbias,
          float* __restrict__ xc_g, float* __restrict__ sz_g) {
    __shared__ float As[11 * 128];   // seq rows l0-3 .. l0+7
    const int l0 = blockIdx.x * 8;
    const int half = blockIdx.y & 1;
    const bool isZ = blockIdx.y >= 2;
    const int tid = threadIdx.x;

    if (FIRST) {
        const int rlo = isZ ? 3 : 0;
        for (int idx = tid + rlo * 128; idx < 11 * 128; idx += 256) {
            const int r = idx >> 7, cc = idx & 127;
            const int l = l0 - 3 + r;
            As[idx] = (l >= 0) ? x0[cc * LSEQ + l] : 0.f;
        }
    } else if (!isZ) {
        // 11 rows x 32 float4
        for (int idx = tid; idx < 11 * 32; idx += 256) {
            const int r = idx >> 5, cq = (idx & 31) * 4;
            const int l = l0 - 3 + r;
            const float4 v = (l >= 0) ? *(const float4*)&seq[l * DM + cq]
                                      : make_float4(0.f, 0.f, 0.f, 0.f);
            *(float4*)&As[r * 128 + cq] = v;
        }
    } else {
        // z-blocks need rows 3..10 only: 8 rows x 32 float4 = 256 tasks
        const int r = 3 + (tid >> 5), cq = (tid & 31) * 4;
        *(float4*)&As[r * 128 + cq] = *(const float4*)&seq[(l0 - 3 + r) * DM + cq];
    }
    __syncthreads();

    const int c = tid & 127;
    const int rg = tid >> 7;          // 0..1 -> out rows rg*4 .. rg*4+3
    const int d = half * 128 + c;

    if (!isZ) {
        float ax[7] = {0.f, 0.f, 0.f, 0.f, 0.f, 0.f, 0.f};
        for (int k4 = 0; k4 < 32; ++k4) {
            float bv[4];
#pragma unroll
            for (int u = 0; u < 4; ++u) bv[u] = Wi[(k4 * 4 + u) * 512 + d];
#pragma unroll
            for (int r = 0; r < 7; ++r) {
                const float4 a4 = *(const float4*)&As[(rg * 4 + r) * 128 + k4 * 4];
                ax[r] += a4.x * bv[0] + a4.y * bv[1] + a4.z * bv[2] + a4.w * bv[3];
            }
        }
        const float w0 = cw[d * 4 + 0], w1 = cw[d * 4 + 1];
        const float w2 = cw[d * 4 + 2], w3 = cw[d * 4 + 3];
        const float cbv = cbias[d];
#pragma unroll
        for (int rr = 0; rr < 4; ++rr) {
            const float v = silu_f(cbv + w0 * ax[rr] + w1 * ax[rr + 1] +
                                   w2 * ax[rr + 2] + w3 * ax[rr + 3]);
            xc_g[(l0 + rg * 4 + rr) * DI + d] = v;
        }
    } else {
        float az[4] = {0.f, 0.f, 0.f, 0.f};
        for (int k4 = 0; k4 < 32; ++k4) {
            float bv[4];
#pragma unroll
            for (int u = 0; u < 4; ++u) bv[u] = Wi[(k4 * 4 + u) * 512 + 256 + d];
#pragma unroll
            for (int r = 0; r < 4; ++r) {
                const float4 a4 = *(const float4*)&As[(rg * 4 + r + 3) * 128 + k4 * 4];
                az[r] += a4.x * bv[0] + a4.y * bv[1] + a4.z * bv[2] + a4.w * bv[3];
            }
        }
#pragma unroll
        for (int rr = 0; rr < 4; ++rr)
            sz_g[(l0 + rg * 4 + rr) * DI + d] = silu_f(az[rr]);
    }
}

// ---------------------------------------------------------------------------
// MID: xc @ Wx -> (dtr, B, C) ; dt = softplus(dtr@Wdt+bdt) ; chunk scan -> P,S.
// grid 576 (4-row chunks); block 256. xproj K-split x4 across all threads.
__global__ __launch_bounds__(256, 4)
void k_mid2(const float* __restrict__ xc_g,
            const float* __restrict__ Wx,
            const float* __restrict__ Wdt, const float* __restrict__ bdt,
            const float* __restrict__ Alog,
            float* __restrict__ dbl_g, float* __restrict__ dt_g,
            float* __restrict__ P, float* __restrict__ S) {
    __shared__ float xcs[CLEN * 256];
    __shared__ float part[4 * 160];
    __shared__ float dtrs[CLEN * 8];
    __shared__ float dbls[CLEN * 32];
    const int c = blockIdx.x;
    const int l0 = c * CLEN;
    const int tid = threadIdx.x;
    const int d = tid;

    // stage 4 xc rows: 256 float4, fully coalesced
    ((float4*)xcs)[tid] = ((const float4*)&xc_g[l0 * DI])[tid];
    __syncthreads();

    // xproj: 160 outputs x 4 K-quarters = 640 tasks over 256 threads
    for (int task = tid; task < 640; task += 256) {
        const int kc = task / 160;
        const int o = task - kc * 160;
        const int r = o / 40, j = o - r * 40;
        const float* xr = &xcs[r * 256 + kc * 64];
        const float* wp = &Wx[(kc * 64) * 40 + j];
        float acc = 0.f;
#pragma unroll 8
        for (int k = 0; k < 64; ++k) acc += xr[k] * wp[k * 40];
        part[kc * 160 + o] = acc;
    }
    __syncthreads();
    if (tid < 160) {
        const float acc = part[tid] + part[160 + tid] + part[320 + tid] + part[480 + tid];
        const int r = tid / 40, j = tid - r * 40;
        if (j < RK) dtrs[r * 8 + j] = acc;
        else {
            dbls[r * 32 + (j - 8)] = acc;
            dbl_g[(l0 + r) * 32 + (j - 8)] = acc;
        }
    }
    __syncthreads();

    // dt = softplus(dtr @ Wdt + bdt)
    float dtv[CLEN], xcv[CLEN];
    {
        float wdt[8];
#pragma unroll
        for (int q = 0; q < 8; ++q) wdt[q] = Wdt[q * DI + d];
        const float bdv = bdt[d];
#pragma unroll
        for (int r = 0; r < CLEN; ++r) {
            float acc = bdv;
#pragma unroll
            for (int q = 0; q < 8; ++q) acc += dtrs[r * 8 + q] * wdt[q];
            dtv[r] = softplus_f(acc);
            dt_g[(l0 + r) * DI + d] = dtv[r];
            xcv[r] = xcs[r * 256 + d];
        }
    }

    // chunk-local scan (thread d holds 16 states)
    float A[16], pr[16], hs[16];
#pragma unroll
    for (int v = 0; v < 4; ++v) {
        const float4 a4 = *(const float4*)&Alog[d * DS + v * 4];
        A[v * 4 + 0] = -__expf(a4.x);
        A[v * 4 + 1] = -__expf(a4.y);
        A[v * 4 + 2] = -__expf(a4.z);
        A[v * 4 + 3] = -__expf(a4.w);
    }
#pragma unroll
    for (int s = 0; s < 16; ++s) { pr[s] = 1.f; hs[s] = 0.f; }
#pragma unroll
    for (int t = 0; t < CLEN; ++t) {
        const float dtt = dtv[t];
        const float uv = dtt * xcv[t];
        const float* Brow = &dbls[t * 32];
#pragma unroll
        for (int s = 0; s < 16; ++s) {
            const float e = __expf(dtt * A[s]);
            pr[s] *= e;
            hs[s] = e * hs[s] + uv * Brow[s];
        }
    }
    const int base = c * NSI + d * DS;
#pragma unroll
    for (int v = 0; v < 4; ++v) {
        *(float4*)&P[base + v * 4] =
            make_float4(pr[v * 4], pr[v * 4 + 1], pr[v * 4 + 2], pr[v * 4 + 3]);
        *(float4*)&S[base + v * 4] =
            make_float4(hs[v * 4], hs[v * 4 + 1], hs[v * 4 + 2], hs[v * 4 + 3]);
    }
}

// ---------------------------------------------------------------------------
// CARRY1: per group of GS chunks, in place: P -> prefix product, S -> local
// carry; emit group aggregates. grid (NG, 16); block 256.
__global__ __launch_bounds__(256, 4)
void k_carry1(float* __restrict__ P, float* __restrict__ S,
              float* __restrict__ Pg, float* __restrict__ Sg) {
    const int g = blockIdx.x;
    const int i = blockIdx.y * 256 + threadIdx.x;
    float G = 0.f, Pp = 1.f;
    const int base = g * GS * NSI + i;
#pragma unroll 8
    for (int k = 0; k < GS; ++k) {
        const int idx = base + k * NSI;
        const float p = P[idx];
        const float s = S[idx];
        S[idx] = G;
        P[idx] = Pp;
        G = p * G + s;
        Pp *= p;
    }
    Pg[g * NSI + i] = Pp;
    Sg[g * NSI + i] = G;
}

// ---------------------------------------------------------------------------
// CARRY2: serial over NG groups: Sg[g] <- carry INTO group g. grid 16 x 256.
__global__ __launch_bounds__(256, 4)
void k_carry2(const float* __restrict__ Pg, float* __restrict__ Sg) {
    const int i = blockIdx.x * 256 + threadIdx.x;
    float G = 0.f;
#pragma unroll 8
    for (int g = 0; g < NG; ++g) {
        const int idx = g * NSI + i;
        const float p = Pg[idx];
        const float s = Sg[idx];
        Sg[idx] = G;
        G = p * G + s;
    }
}

// ---------------------------------------------------------------------------
// TAIL: h0 = Sloc + Pprefix * Ggroup ; re-scan + gate + out-GEMM (K-split x4)
// + rmsnorm. grid 576; block 256.
template<bool LAST>
__global__ __launch_bounds__(256, 2)
void k_tail(const float* __restrict__ dt_g, const float* __restrict__ xc_g,
            const float* __restrict__ dbl_g, const float* __restrict__ Alog,
            const float* __restrict__ Sloc, const float* __restrict__ Ppre,
            const float* __restrict__ Gc, const float* __restrict__ Dp,
            const float* __restrict__ sz_g, const float* __restrict__ Wo,
            const float* __restrict__ rmsw, float* __restrict__ seq,
            float* __restrict__ out) {
    __shared__ float dbls[CLEN * 32];     // 128
    __shared__ float Ys[CLEN * 256];
    __shared__ float partO[4 * CLEN * 128];   // [kg][r][cc]
    __shared__ float Os[CLEN * 129];
    __shared__ float red[CLEN * 32];
    __shared__ float scaleS[CLEN];
    const int c = blockIdx.x;
    const int g = c / GS;
    const int l0 = c * CLEN;
    const int tid = threadIdx.x;
    const int d = tid;

    if (tid < CLEN * 32) dbls[tid] = dbl_g[l0 * 32 + tid];

    float A[16], h[16];
#pragma unroll
    for (int v = 0; v < 4; ++v) {
        const float4 a4 = *(const float4*)&Alog[d * DS + v * 4];
        A[v * 4 + 0] = -__expf(a4.x);
        A[v * 4 + 1] = -__expf(a4.y);
        A[v * 4 + 2] = -__expf(a4.z);
        A[v * 4 + 3] = -__expf(a4.w);
        const float4 s4 = *(const float4*)&Sloc[c * NSI + d * DS + v * 4];
        const float4 p4 = *(const float4*)&Ppre[c * NSI + d * DS + v * 4];
        const float4 g4 = *(const float4*)&Gc[g * NSI + d * DS + v * 4];
        h[v * 4 + 0] = s4.x + p4.x * g4.x;
        h[v * 4 + 1] = s4.y + p4.y * g4.y;
        h[v * 4 + 2] = s4.z + p4.z * g4.z;
        h[v * 4 + 3] = s4.w + p4.w * g4.w;
    }
    float dtv[CLEN], xcv[CLEN], szv[CLEN];
#pragma unroll
    for (int r = 0; r < CLEN; ++r) {
        dtv[r] = dt_g[(l0 + r) * DI + d];
        xcv[r] = xc_g[(l0 + r) * DI + d];
        szv[r] = sz_g[(l0 + r) * DI + d];
    }
    const float dskip = Dp[d];
    __syncthreads();
#pragma unroll
    for (int t = 0; t < CLEN; ++t) {
        const float dtt = dtv[t];
        const float uv = dtt * xcv[t];
        float sum = 0.f;
#pragma unroll
        for (int s = 0; s < 16; ++s) {
            const float e = __expf(dtt * A[s]);
            h[s] = e * h[s] + uv * dbls[t * 32 + s];
            sum += h[s] * dbls[t * 32 + 16 + s];
        }
        Ys[t * 256 + d] = (sum + dskip * xcv[t]) * szv[t];
    }
    __syncthreads();

    // out-GEMM: 64 cc-pairs x 4 K-groups (K=64 each), float2 Wo loads
    {
        const int ccp = tid & 63;
        const int kg = tid >> 6;
        float acc[CLEN][2];
#pragma unroll
        for (int r = 0; r < CLEN; ++r) { acc[r][0] = 0.f; acc[r][1] = 0.f; }
        const float* wp = &Wo[(kg * 64) * DM + ccp * 2];
        const float* yp = &Ys[kg * 64];
#pragma unroll 8
        for (int k = 0; k < 64; ++k) {
            const float2 w2 = *(const float2*)(wp + k * DM);
#pragma unroll
            for (int r = 0; r < CLEN; ++r) {
                const float yv = yp[r * 256 + k];
                acc[r][0] += yv * w2.x;
                acc[r][1] += yv * w2.y;
            }
        }
#pragma unroll
        for (int r = 0; r < CLEN; ++r) {
            partO[(kg * CLEN + r) * 128 + ccp * 2 + 0] = acc[r][0];
            partO[(kg * CLEN + r) * 128 + ccp * 2 + 1] = acc[r][1];
        }
        __syncthreads();
        for (int idx = tid; idx < CLEN * 128; idx += 256) {
            const int r = idx >> 7, cc = idx & 127;
            Os[r * 129 + cc] = partO[(0 * CLEN + r) * 128 + cc] +
                               partO[(1 * CLEN + r) * 128 + cc] +
                               partO[(2 * CLEN + r) * 128 + cc] +
                               partO[(3 * CLEN + r) * 128 + cc];
        }
        __syncthreads();
    }

    // rmsnorm + store
    if (tid < CLEN * 32) {
        const int r = tid >> 5, part = tid & 31;
        float ss = 0.f;
#pragma unroll
        for (int i = 0; i < 4; ++i) {
            const float v = Os[r * 129 + part * 4 + i];
            ss += v * v;
        }
        red[tid] = ss;
    }
    __syncthreads();
    if (tid < CLEN) {
        float ss = 0.f;
#pragma unroll
        for (int p = 0; p < 32; ++p) ss += red[tid * 32 + p];
        scaleS[tid] = rsqrtf(ss * (1.f / DM) + EPSF);
    }
    __syncthreads();
    if (LAST) {
        for (int idx = tid; idx < CLEN * DM; idx += 256) {
            const int r = idx >> 7, cc = idx & 127;
            out[cc * LSEQ + (l0 + r)] = Os[r * 129 + cc] * scaleS[r] * rmsw[cc];
        }
    } else {
        for (int idx = tid; idx < CLEN * DM; idx += 256) {
            const int r = idx >> 7, cc = idx & 127;
            seq[(l0 + r) * DM + cc] = Os[r * 129 + cc] * scaleS[r] * rmsw[cc];
        }
    }
}

// ---------------------------------------------------------------------------
extern "C" void kernel_launch(void* const* d_in, const int* in_sizes, int n_in,
                              void* d_out, int out_size, void* d_ws, size_t ws_size,
                              hipStream_t stream) {
    const float* x    = (const float*)d_in[0];
    const float* W_in = (const float*)d_in[1];
    const float* cw   = (const float*)d_in[2];
    const float* cb   = (const float*)d_in[3];
    const float* Wx   = (const float*)d_in[4];
    const float* Wdt  = (const float*)d_in[5];
    const float* bdt  = (const float*)d_in[6];
    const float* Alog = (const float*)d_in[7];
    const float* Dp   = (const float*)d_in[8];
    const float* Wo   = (const float*)d_in[9];
    const float* rmsw = (const float*)d_in[10];
    float* out = (float*)d_out;

    float* ws   = (float*)d_ws;
    float* seq  = ws; ws += LSEQ * DM;
    float* szb  = ws; ws += LSEQ * DI;
    float* xcb  = ws; ws += LSEQ * DI;
    float* dtb  = ws; ws += LSEQ * DI;
    float* dblb = ws; ws += LSEQ * 32;
    float* Pb   = ws; ws += NCH * NSI;
    float* Sb   = ws; ws += NCH * NSI;
    float* Pgb  = ws; ws += NG * NSI;
    float* Sgb  = ws; ws += NG * NSI;

    for (int layer = 0; layer < 8; ++layer) {
        const float* Wi_l   = W_in + (size_t)layer * DM * 512;
        const float* cw_l   = cw   + (size_t)layer * DI * 4;
        const float* cb_l   = cb   + (size_t)layer * DI;
        const float* Wx_l   = Wx   + (size_t)layer * DI * 40;
        const float* Wdt_l  = Wdt  + (size_t)layer * RK * DI;
        const float* bdt_l  = bdt  + (size_t)layer * DI;
        const float* Alog_l = Alog + (size_t)layer * DI * DS;
        const float* Dp_l   = Dp   + (size_t)layer * DI;
        const float* Wo_l   = Wo   + (size_t)layer * DI * DM;
        const float* rmsw_l = rmsw + (size_t)layer * DM;

        if (layer == 0)
            k_in<true><<<dim3(288, 4), 256, 0, stream>>>(seq, x, Wi_l, cw_l, cb_l,
                                                         xcb, szb);
        else
            k_in<false><<<dim3(288, 4), 256, 0, stream>>>(seq, x, Wi_l, cw_l, cb_l,
                                                          xcb, szb);

        k_mid2<<<NCH, 256, 0, stream>>>(xcb, Wx_l, Wdt_l, bdt_l, Alog_l,
                                        dblb, dtb, Pb, Sb);

        k_carry1<<<dim3(NG, 16), 256, 0, stream>>>(Pb, Sb, Pgb, Sgb);
        k_carry2<<<16, 256, 0, stream>>>(Pgb, Sgb);

        if (layer == 7)
            k_tail<true><<<NCH, 256, 0, stream>>>(dtb, xcb, dblb, Alog_l, Sb, Pb,
                                                  Sgb, Dp_l, szb, Wo_l, rmsw_l,
                                                  seq, out);
        else
            k_tail<false><<<NCH, 256, 0, stream>>>(dtb, xcb, dblb, Alog_l, Sb, Pb,
                                                   Sgb, Dp_l, szb, Wo_l, rmsw_l,
                                                   seq, out);
    }
}

// Round 14
// 555.805 us; speedup vs baseline: 1.1688x; 1.0057x over previous
//
#include <hip/hip_runtime.h>
#include <math.h>

#define LSEQ 2304
#define DM 128
#define DI 256
#define DS 16
#define RK 8
#define NCH 576     // 4-row chunks
#define CLEN 4
#define NG 24       // carry groups
#define GS 24       // chunks per group (NG*GS == NCH)
#define NSI (DI*DS) // 4096 state indices
#define EPSF 1e-5f

__device__ __forceinline__ float silu_f(float s) { return s / (1.f + __expf(-s)); }
__device__ __forceinline__ float softplus_f(float x) { return (x > 20.f) ? x : log1pf(__expf(x)); }

// ---------------------------------------------------------------------------
// IN: in-proj GEMM + conv4 + silu -> xc ; silu(z) -> sz.
// grid (144, 4): 16-row x 128-col tiles. y=0/1: x-halves (conv, 3-row halo
// recomputed in-register); y=2/3: z-halves. block 256 = 128 cols x 2 rowgroups(8).
template<bool FIRST>
__global__ __launch_bounds__(256, 4)
void k_in(const float* __restrict__ seq, const float* __restrict__ x0,
          const float* __restrict__ Wi,
          const float* __restrict__ cw, const float* __restrict__ cbias,
          float* __restrict__ xc_g, float* __restrict__ sz_g) {
    __shared__ float As[19 * 128];   // seq rows l0-3 .. l0+15
    const int l0 = blockIdx.x * 16;
    const int half = blockIdx.y & 1;
    const bool isZ = blockIdx.y >= 2;
    const int tid = threadIdx.x;

    if (FIRST) {
        const int rlo = isZ ? 3 : 0;
        for (int idx = tid + rlo * 128; idx < 19 * 128; idx += 256) {
            const int r = idx >> 7, cc = idx & 127;
            const int l = l0 - 3 + r;
            As[idx] = (l >= 0) ? x0[cc * LSEQ + l] : 0.f;
        }
    } else if (!isZ) {
        // 19 rows x 32 float4
        for (int idx = tid; idx < 19 * 32; idx += 256) {
            const int r = idx >> 5, cq = (idx & 31) * 4;
            const int l = l0 - 3 + r;
            const float4 v = (l >= 0) ? *(const float4*)&seq[l * DM + cq]
                                      : make_float4(0.f, 0.f, 0.f, 0.f);
            *(float4*)&As[r * 128 + cq] = v;
        }
    } else {
        // z-blocks need rows 3..18 only: 16 rows x 32 float4 = 512 tasks
        for (int idx = tid; idx < 16 * 32; idx += 256) {
            const int r = 3 + (idx >> 5), cq = (idx & 31) * 4;
            *(float4*)&As[r * 128 + cq] =
                *(const float4*)&seq[(l0 - 3 + r) * DM + cq];
        }
    }
    __syncthreads();

    const int c = tid & 127;
    const int rg = tid >> 7;          // 0..1 -> out rows rg*8 .. rg*8+7
    const int d = half * 128 + c;

    if (!isZ) {
        float ax[11];
#pragma unroll
        for (int r = 0; r < 11; ++r) ax[r] = 0.f;
        for (int k4 = 0; k4 < 32; ++k4) {
            float bv[4];
#pragma unroll
            for (int u = 0; u < 4; ++u) bv[u] = Wi[(k4 * 4 + u) * 512 + d];
#pragma unroll
            for (int r = 0; r < 11; ++r) {
                const float4 a4 = *(const float4*)&As[(rg * 8 + r) * 128 + k4 * 4];
                ax[r] += a4.x * bv[0] + a4.y * bv[1] + a4.z * bv[2] + a4.w * bv[3];
            }
        }
        const float w0 = cw[d * 4 + 0], w1 = cw[d * 4 + 1];
        const float w2 = cw[d * 4 + 2], w3 = cw[d * 4 + 3];
        const float cbv = cbias[d];
#pragma unroll
        for (int rr = 0; rr < 8; ++rr) {
            const float v = silu_f(cbv + w0 * ax[rr] + w1 * ax[rr + 1] +
                                   w2 * ax[rr + 2] + w3 * ax[rr + 3]);
            xc_g[(l0 + rg * 8 + rr) * DI + d] = v;
        }
    } else {
        float az[8];
#pragma unroll
        for (int r = 0; r < 8; ++r) az[r] = 0.f;
        for (int k4 = 0; k4 < 32; ++k4) {
            float bv[4];
#pragma unroll
            for (int u = 0; u < 4; ++u) bv[u] = Wi[(k4 * 4 + u) * 512 + 256 + d];
#pragma unroll
            for (int r = 0; r < 8; ++r) {
                const float4 a4 = *(const float4*)&As[(rg * 8 + r + 3) * 128 + k4 * 4];
                az[r] += a4.x * bv[0] + a4.y * bv[1] + a4.z * bv[2] + a4.w * bv[3];
            }
        }
#pragma unroll
        for (int rr = 0; rr < 8; ++rr)
            sz_g[(l0 + rg * 8 + rr) * DI + d] = silu_f(az[rr]);
    }
}

// ---------------------------------------------------------------------------
// MID: xc @ Wx -> (dtr, B, C) ; dt = softplus(dtr@Wdt+bdt) ; chunk scan -> P,S.
// grid 576 (4-row chunks); block 256. xproj K-split x4 across all threads.
__global__ __launch_bounds__(256, 4)
void k_mid2(const float* __restrict__ xc_g,
            const float* __restrict__ Wx,
            const float* __restrict__ Wdt, const float* __restrict__ bdt,
            const float* __restrict__ Alog,
            float* __restrict__ dbl_g, float* __restrict__ dt_g,
            float* __restrict__ P, float* __restrict__ S) {
    __shared__ float xcs[CLEN * 256];
    __shared__ float part[4 * 160];
    __shared__ float dtrs[CLEN * 8];
    __shared__ float dbls[CLEN * 32];
    const int c = blockIdx.x;
    const int l0 = c * CLEN;
    const int tid = threadIdx.x;
    const int d = tid;

    // stage 4 xc rows: 256 float4, fully coalesced
    ((float4*)xcs)[tid] = ((const float4*)&xc_g[l0 * DI])[tid];
    __syncthreads();

    // xproj: 160 outputs x 4 K-quarters = 640 tasks over 256 threads
    for (int task = tid; task < 640; task += 256) {
        const int kc = task / 160;
        const int o = task - kc * 160;
        const int r = o / 40, j = o - r * 40;
        const float* xr = &xcs[r * 256 + kc * 64];
        const float* wp = &Wx[(kc * 64) * 40 + j];
        float acc = 0.f;
#pragma unroll 8
        for (int k = 0; k < 64; ++k) acc += xr[k] * wp[k * 40];
        part[kc * 160 + o] = acc;
    }
    __syncthreads();
    if (tid < 160) {
        const float acc = part[tid] + part[160 + tid] + part[320 + tid] + part[480 + tid];
        const int r = tid / 40, j = tid - r * 40;
        if (j < RK) dtrs[r * 8 + j] = acc;
        else {
            dbls[r * 32 + (j - 8)] = acc;
            dbl_g[(l0 + r) * 32 + (j - 8)] = acc;
        }
    }
    __syncthreads();

    // dt = softplus(dtr @ Wdt + bdt)
    float dtv[CLEN], xcv[CLEN];
    {
        float wdt[8];
#pragma unroll
        for (int q = 0; q < 8; ++q) wdt[q] = Wdt[q * DI + d];
        const float bdv = bdt[d];
#pragma unroll
        for (int r = 0; r < CLEN; ++r) {
            float acc = bdv;
#pragma unroll
            for (int q = 0; q < 8; ++q) acc += dtrs[r * 8 + q] * wdt[q];
            dtv[r] = softplus_f(acc);
            dt_g[(l0 + r) * DI + d] = dtv[r];
            xcv[r] = xcs[r * 256 + d];
        }
    }

    // chunk-local scan (thread d holds 16 states)
    float A[16], pr[16], hs[16];
#pragma unroll
    for (int v = 0; v < 4; ++v) {
        const float4 a4 = *(const float4*)&Alog[d * DS + v * 4];
        A[v * 4 + 0] = -__expf(a4.x);
        A[v * 4 + 1] = -__expf(a4.y);
        A[v * 4 + 2] = -__expf(a4.z);
        A[v * 4 + 3] = -__expf(a4.w);
    }
#pragma unroll
    for (int s = 0; s < 16; ++s) { pr[s] = 1.f; hs[s] = 0.f; }
#pragma unroll
    for (int t = 0; t < CLEN; ++t) {
        const float dtt = dtv[t];
        const float uv = dtt * xcv[t];
        const float* Brow = &dbls[t * 32];
#pragma unroll
        for (int s = 0; s < 16; ++s) {
            const float e = __expf(dtt * A[s]);
            pr[s] *= e;
            hs[s] = e * hs[s] + uv * Brow[s];
        }
    }
    const int base = c * NSI + d * DS;
#pragma unroll
    for (int v = 0; v < 4; ++v) {
        *(float4*)&P[base + v * 4] =
            make_float4(pr[v * 4], pr[v * 4 + 1], pr[v * 4 + 2], pr[v * 4 + 3]);
        *(float4*)&S[base + v * 4] =
            make_float4(hs[v * 4], hs[v * 4 + 1], hs[v * 4 + 2], hs[v * 4 + 3]);
    }
}

// ---------------------------------------------------------------------------
// CARRY1: per group of GS chunks, in place: P -> prefix product, S -> local
// carry; emit group aggregates. grid (NG, 16); block 256.
__global__ __launch_bounds__(256, 4)
void k_carry1(float* __restrict__ P, float* __restrict__ S,
              float* __restrict__ Pg, float* __restrict__ Sg) {
    const int g = blockIdx.x;
    const int i = blockIdx.y * 256 + threadIdx.x;
    float G = 0.f, Pp = 1.f;
    const int base = g * GS * NSI + i;
#pragma unroll 8
    for (int k = 0; k < GS; ++k) {
        const int idx = base + k * NSI;
        const float p = P[idx];
        const float s = S[idx];
        S[idx] = G;
        P[idx] = Pp;
        G = p * G + s;
        Pp *= p;
    }
    Pg[g * NSI + i] = Pp;
    Sg[g * NSI + i] = G;
}

// ---------------------------------------------------------------------------
// CARRY2: serial over NG groups: Sg[g] <- carry INTO group g. grid 16 x 256.
__global__ __launch_bounds__(256, 4)
void k_carry2(const float* __restrict__ Pg, float* __restrict__ Sg) {
    const int i = blockIdx.x * 256 + threadIdx.x;
    float G = 0.f;
#pragma unroll 8
    for (int g = 0; g < NG; ++g) {
        const int idx = g * NSI + i;
        const float p = Pg[idx];
        const float s = Sg[idx];
        Sg[idx] = G;
        G = p * G + s;
    }
}

// ---------------------------------------------------------------------------
// TAIL: h0 = Sloc + Pprefix * Ggroup ; re-scan + gate + out-GEMM (K-split x4)
// + rmsnorm. grid 576; block 256.
template<bool LAST>
__global__ __launch_bounds__(256, 3)
void k_tail(const float* __restrict__ dt_g, const float* __restrict__ xc_g,
            const float* __restrict__ dbl_g, const float* __restrict__ Alog,
            const float* __restrict__ Sloc, const float* __restrict__ Ppre,
            const float* __restrict__ Gc, const float* __restrict__ Dp,
            const float* __restrict__ sz_g, const float* __restrict__ Wo,
            const float* __restrict__ rmsw, float* __restrict__ seq,
            float* __restrict__ out) {
    __shared__ float dbls[CLEN * 32];     // 128
    __shared__ float Ys[CLEN * 256];
    __shared__ float partO[4 * CLEN * 128];   // [kg][r][cc]
    __shared__ float Os[CLEN * 129];
    __shared__ float red[CLEN * 32];
    __shared__ float scaleS[CLEN];
    const int c = blockIdx.x;
    const int g = c / GS;
    const int l0 = c * CLEN;
    const int tid = threadIdx.x;
    const int d = tid;

    if (tid < CLEN * 32) dbls[tid] = dbl_g[l0 * 32 + tid];

    float A[16], h[16];
#pragma unroll
    for (int v = 0; v < 4; ++v) {
        const float4 a4 = *(const float4*)&Alog[d * DS + v * 4];
        A[v * 4 + 0] = -__expf(a4.x);
        A[v * 4 + 1] = -__expf(a4.y);
        A[v * 4 + 2] = -__expf(a4.z);
        A[v * 4 + 3] = -__expf(a4.w);
        const float4 s4 = *(const float4*)&Sloc[c * NSI + d * DS + v * 4];
        const float4 p4 = *(const float4*)&Ppre[c * NSI + d * DS + v * 4];
        const float4 g4 = *(const float4*)&Gc[g * NSI + d * DS + v * 4];
        h[v * 4 + 0] = s4.x + p4.x * g4.x;
        h[v * 4 + 1] = s4.y + p4.y * g4.y;
        h[v * 4 + 2] = s4.z + p4.z * g4.z;
        h[v * 4 + 3] = s4.w + p4.w * g4.w;
    }
    float dtv[CLEN], xcv[CLEN], szv[CLEN];
#pragma unroll
    for (int r = 0; r < CLEN; ++r) {
        dtv[r] = dt_g[(l0 + r) * DI + d];
        xcv[r] = xc_g[(l0 + r) * DI + d];
        szv[r] = sz_g[(l0 + r) * DI + d];
    }
    const float dskip = Dp[d];
    __syncthreads();
#pragma unroll
    for (int t = 0; t < CLEN; ++t) {
        const float dtt = dtv[t];
        const float uv = dtt * xcv[t];
        float sum = 0.f;
#pragma unroll
        for (int s = 0; s < 16; ++s) {
            const float e = __expf(dtt * A[s]);
            h[s] = e * h[s] + uv * dbls[t * 32 + s];
            sum += h[s] * dbls[t * 32 + 16 + s];
        }
        Ys[t * 256 + d] = (sum + dskip * xcv[t]) * szv[t];
    }
    __syncthreads();

    // out-GEMM: 64 cc-pairs x 4 K-groups (K=64 each), float2 Wo loads
    {
        const int ccp = tid & 63;
        const int kg = tid >> 6;
        float acc[CLEN][2];
#pragma unroll
        for (int r = 0; r < CLEN; ++r) { acc[r][0] = 0.f; acc[r][1] = 0.f; }
        const float* wp = &Wo[(kg * 64) * DM + ccp * 2];
        const float* yp = &Ys[kg * 64];
#pragma unroll 8
        for (int k = 0; k < 64; ++k) {
            const float2 w2 = *(const float2*)(wp + k * DM);
#pragma unroll
            for (int r = 0; r < CLEN; ++r) {
                const float yv = yp[r * 256 + k];
                acc[r][0] += yv * w2.x;
                acc[r][1] += yv * w2.y;
            }
        }
#pragma unroll
        for (int r = 0; r < CLEN; ++r) {
            partO[(kg * CLEN + r) * 128 + ccp * 2 + 0] = acc[r][0];
            partO[(kg * CLEN + r) * 128 + ccp * 2 + 1] = acc[r][1];
        }
        __syncthreads();
        for (int idx = tid; idx < CLEN * 128; idx += 256) {
            const int r = idx >> 7, cc = idx & 127;
            Os[r * 129 + cc] = partO[(0 * CLEN + r) * 128 + cc] +
                               partO[(1 * CLEN + r) * 128 + cc] +
                               partO[(2 * CLEN + r) * 128 + cc] +
                               partO[(3 * CLEN + r) * 128 + cc];
        }
        __syncthreads();
    }

    // rmsnorm + store
    if (tid < CLEN * 32) {
        const int r = tid >> 5, part = tid & 31;
        float ss = 0.f;
#pragma unroll
        for (int i = 0; i < 4; ++i) {
            const float v = Os[r * 129 + part * 4 + i];
            ss += v * v;
        }
        red[tid] = ss;
    }
    __syncthreads();
    if (tid < CLEN) {
        float ss = 0.f;
#pragma unroll
        for (int p = 0; p < 32; ++p) ss += red[tid * 32 + p];
        scaleS[tid] = rsqrtf(ss * (1.f / DM) + EPSF);
    }
    __syncthreads();
    if (LAST) {
        for (int idx = tid; idx < CLEN * DM; idx += 256) {
            const int r = idx >> 7, cc = idx & 127;
            out[cc * LSEQ + (l0 + r)] = Os[r * 129 + cc] * scaleS[r] * rmsw[cc];
        }
    } else {
        for (int idx = tid; idx < CLEN * DM; idx += 256) {
            const int r = idx >> 7, cc = idx & 127;
            seq[(l0 + r) * DM + cc] = Os[r * 129 + cc] * scaleS[r] * rmsw[cc];
        }
    }
}

// ---------------------------------------------------------------------------
extern "C" void kernel_launch(void* const* d_in, const int* in_sizes, int n_in,
                              void* d_out, int out_size, void* d_ws, size_t ws_size,
                              hipStream_t stream) {
    const float* x    = (const float*)d_in[0];
    const float* W_in = (const float*)d_in[1];
    const float* cw   = (const float*)d_in[2];
    const float* cb   = (const float*)d_in[3];
    const float* Wx   = (const float*)d_in[4];
    const float* Wdt  = (const float*)d_in[5];
    const float* bdt  = (const float*)d_in[6];
    const float* Alog = (const float*)d_in[7];
    const float* Dp   = (const float*)d_in[8];
    const float* Wo   = (const float*)d_in[9];
    const float* rmsw = (const float*)d_in[10];
    float* out = (float*)d_out;

    float* ws   = (float*)d_ws;
    float* seq  = ws; ws += LSEQ * DM;
    float* szb  = ws; ws += LSEQ * DI;
    float* xcb  = ws; ws += LSEQ * DI;
    float* dtb  = ws; ws += LSEQ * DI;
    float* dblb = ws; ws += LSEQ * 32;
    float* Pb   = ws; ws += NCH * NSI;
    float* Sb   = ws; ws += NCH * NSI;
    float* Pgb  = ws; ws += NG * NSI;
    float* Sgb  = ws; ws += NG * NSI;

    for (int layer = 0; layer < 8; ++layer) {
        const float* Wi_l   = W_in + (size_t)layer * DM * 512;
        const float* cw_l   = cw   + (size_t)layer * DI * 4;
        const float* cb_l   = cb   + (size_t)layer * DI;
        const float* Wx_l   = Wx   + (size_t)layer * DI * 40;
        const float* Wdt_l  = Wdt  + (size_t)layer * RK * DI;
        const float* bdt_l  = bdt  + (size_t)layer * DI;
        const float* Alog_l = Alog + (size_t)layer * DI * DS;
        const float* Dp_l   = Dp   + (size_t)layer * DI;
        const float* Wo_l   = Wo   + (size_t)layer * DI * DM;
        const float* rmsw_l = rmsw + (size_t)layer * DM;

        if (layer == 0)
            k_in<true><<<dim3(144, 4), 256, 0, stream>>>(seq, x, Wi_l, cw_l, cb_l,
                                                         xcb, szb);
        else
            k_in<false><<<dim3(144, 4), 256, 0, stream>>>(seq, x, Wi_l, cw_l, cb_l,
                                                          xcb, szb);

        k_mid2<<<NCH, 256, 0, stream>>>(xcb, Wx_l, Wdt_l, bdt_l, Alog_l,
                                        dblb, dtb, Pb, Sb);

        k_carry1<<<dim3(NG, 16), 256, 0, stream>>>(Pb, Sb, Pgb, Sgb);
        k_carry2<<<16, 256, 0, stream>>>(Pgb, Sgb);

        if (layer == 7)
            k_tail<true><<<NCH, 256, 0, stream>>>(dtb, xcb, dblb, Alog_l, Sb, Pb,
                                                  Sgb, Dp_l, szb, Wo_l, rmsw_l,
                                                  seq, out);
        else
            k_tail<false><<<NCH, 256, 0, stream>>>(dtb, xcb, dblb, Alog_l, Sb, Pb,
                                                   Sgb, Dp_l, szb, Wo_l, rmsw_l,
                                                   seq, out);
    }
}